// Round 1
// baseline (440.305 us; speedup 1.0000x reference)
//
#include <hip/hip_runtime.h>

// Blur / upfirdn2d: y[i,j] = sum_{u,v} K[u][v] * x[i+1-u, j+1-v], zero pad.
// x: (8,128,256,256) fp32 -> 1024 planes of 256x256. Output same shape fp32.
//
// Memory-bound streaming stencil. Each thread: 4 output cols (float4) x 8
// output rows, streaming 11 input rows through registers. One wave covers a
// full 256-wide row -> perfectly coalesced loads/stores.

#define HH 256
#define WW 256

__global__ __launch_bounds__(256) void blur_kernel(
    const float* __restrict__ x, const float* __restrict__ k4,
    float* __restrict__ out)
{
    const int tid   = threadIdx.x;
    const int cx    = tid & 63;        // 64 col groups * 4 cols = 256 cols
    const int ry    = tid >> 6;        // 0..3 row strips
    const int j     = cx << 2;         // output col base
    const int chunk = blockIdx.x;      // 8 chunks of 32 rows
    const int plane = blockIdx.y;      // 1024 planes (B*C)
    const int i0    = chunk * 32 + ry * 8;   // first output row of this thread

    // Kr[u][t] = K[u][3-t]  (reversed cols so inner loop is a sliding dot)
    float Kr[4][4];
#pragma unroll
    for (int u = 0; u < 4; ++u)
#pragma unroll
        for (int t = 0; t < 4; ++t)
            Kr[u][t] = k4[u * 4 + (3 - t)];

    const float* xp = x + (size_t)plane * (HH * WW);

    float acc[8][4];
#pragma unroll
    for (int r = 0; r < 8; ++r)
#pragma unroll
        for (int c = 0; c < 4; ++c) acc[r][c] = 0.f;

    // Stream input rows i0-2 .. i0+8 (11 rows). Row r contributes to output
    // rows r-1 .. r+2 (u = 0..3 with i = r+u-1).
#pragma unroll
    for (int rr = 0; rr < 11; ++rr) {
        const int r = i0 - 2 + rr;
        float w0, w1, w2, w3, w4, w5, w6;   // cols j-2 .. j+4
        if ((unsigned)r < (unsigned)HH) {
            const float* row = xp + r * WW + j;
            if (j >= 2) {                    // only cx==0 fails
                float2 l = *(const float2*)(row - 2);
                w0 = l.x; w1 = l.y;
            } else { w0 = 0.f; w1 = 0.f; }
            float4 m = *(const float4*)(row);       // 16B aligned
            w2 = m.x; w3 = m.y; w4 = m.z; w5 = m.w;
            w6 = (j + 4 < WW) ? row[4] : 0.f;       // only cx==63 fails
        } else {
            w0 = w1 = w2 = w3 = w4 = w5 = w6 = 0.f;
        }
        const float wv[7] = {w0, w1, w2, w3, w4, w5, w6};
#pragma unroll
        for (int u = 0; u < 4; ++u) {
            const int lo = rr + u - 3;      // local output row
            if (lo >= 0 && lo < 8) {        // compile-time resolved
#pragma unroll
                for (int c = 0; c < 4; ++c)
#pragma unroll
                    for (int t = 0; t < 4; ++t)
                        acc[lo][c] += Kr[u][t] * wv[c + t];
            }
        }
    }

    float* op = out + (size_t)plane * (HH * WW) + (size_t)i0 * WW + j;
#pragma unroll
    for (int r = 0; r < 8; ++r) {
        *(float4*)(op + (size_t)r * WW) =
            make_float4(acc[r][0], acc[r][1], acc[r][2], acc[r][3]);
    }
}

extern "C" void kernel_launch(void* const* d_in, const int* in_sizes, int n_in,
                              void* d_out, int out_size, void* d_ws, size_t ws_size,
                              hipStream_t stream) {
    const float* x = (const float*)d_in[0];   // 8*128*256*256 fp32
    const float* k = (const float*)d_in[1];   // 16 fp32 (4x4 FIR kernel)
    float* out = (float*)d_out;               // same shape as x, fp32

    dim3 grid(8, 1024);   // 8 row-chunks x (B*C = 1024) planes
    blur_kernel<<<grid, 256, 0, stream>>>(x, k, out);
}

// Round 2
// 432.135 us; speedup vs baseline: 1.0189x; 1.0189x over previous
//
#include <hip/hip_runtime.h>

// Blur / upfirdn2d: y[i,j] = sum_{u,v} K[u][v] * x[i+1-u, j+1-v], zero pad (2,1).
// x: (8,128,256,256) fp32 -> 1024 planes of 256x256. Output same shape fp32.
//
// R2: LDS-staged tile. Per block: 32 output rows x 256 cols of one plane.
// Load phase is BRANCH-FREE (clamped addresses + zero masks) so all 9 float4
// global loads per thread issue back-to-back -> high MLP, HBM-BW-bound.
// Compute phase reads only LDS (halo cols pre-zeroed) -> branch-free.

#define HH 256
#define WW 256
#define TR 32            // output rows per block
#define LR (TR + 3)      // 35 staged input rows
#define LSTR 264         // LDS row stride in floats: 4 pad | 256 data | 4 pad

__global__ __launch_bounds__(256) void blur_kernel(
    const float* __restrict__ x, const float* __restrict__ k4,
    float* __restrict__ out)
{
    __shared__ float tile[LR * LSTR];   // 36,960 B

    const int tid   = threadIdx.x;
    const int lane  = tid & 63;         // 64 lanes x float4 = 256 cols
    const int warp  = tid >> 6;         // 4 waves
    const int chunk = blockIdx.x;       // 8 chunks of 32 rows
    const int plane = blockIdx.y;       // 1024 planes (B*C)
    const int i0    = chunk * TR;

    const float* xp = x + (size_t)plane * (HH * WW);

    // Kernel weights, column-reversed: Kr[u][t] = K[u][3-t]
    float Kr[4][4];
#pragma unroll
    for (int u = 0; u < 4; ++u)
#pragma unroll
        for (int t = 0; t < 4; ++t)
            Kr[u][t] = k4[u * 4 + (3 - t)];

    // ---- zero the 4-col halo pads (cols 0..3 and 260..263, all 35 rows) ----
    for (int idx = tid; idx < LR * 8; idx += 256) {
        const int row = idx >> 3, c8 = idx & 7;
        const int col = (c8 < 4) ? c8 : (260 + (c8 - 4));
        tile[row * LSTR + col] = 0.f;
    }

    // ---- stage LR rows x 256 cols into LDS, branch-free loads ----
    // wave w handles LDS rows w, w+4, ..., w+32 (9 slots; last unused for w=3)
    float4 v[9];
#pragma unroll
    for (int k = 0; k < 9; ++k) {
        const int l  = warp + 4 * k;            // LDS row (may be 35 for w=3)
        const int g  = i0 - 2 + l;              // global input row
        const int gc = min(max(g, 0), HH - 1);  // clamped (always valid addr)
        v[k] = *(const float4*)(xp + (size_t)gc * WW + 4 * lane);
        if (g != gc) v[k] = make_float4(0.f, 0.f, 0.f, 0.f);  // OOB row -> 0
    }
#pragma unroll
    for (int k = 0; k < 9; ++k) {
        const int l = warp + 4 * k;
        if (l < LR)   // wave-uniform; only trims w=3's 9th slot
            *(float4*)(&tile[l * LSTR + 4 + 4 * lane]) = v[k];
    }

    __syncthreads();

    // ---- compute: each thread = 8 output rows x 4 cols, sliding 11 LDS rows
    float acc[8][4];
#pragma unroll
    for (int r = 0; r < 8; ++r)
#pragma unroll
        for (int c = 0; c < 4; ++c) acc[r][c] = 0.f;

    const int obase = warp * 8;                 // thread's first local out row
#pragma unroll
    for (int rr = 0; rr < 11; ++rr) {
        const float* p = &tile[(obase + rr) * LSTR + 4 * lane + 2];
        const float wv[7] = {p[0], p[1], p[2], p[3], p[4], p[5], p[6]};
#pragma unroll
        for (int u = 0; u < 4; ++u) {
            const int lo = rr + u - 3;          // local output row
            if (lo >= 0 && lo < 8) {            // compile-time resolved
#pragma unroll
                for (int c = 0; c < 4; ++c)
#pragma unroll
                    for (int t = 0; t < 4; ++t)
                        acc[lo][c] += Kr[u][t] * wv[c + t];
            }
        }
    }

    float* op = out + (size_t)plane * (HH * WW)
                    + (size_t)(i0 + obase) * WW + 4 * lane;
#pragma unroll
    for (int r = 0; r < 8; ++r)
        *(float4*)(op + (size_t)r * WW) =
            make_float4(acc[r][0], acc[r][1], acc[r][2], acc[r][3]);
}

extern "C" void kernel_launch(void* const* d_in, const int* in_sizes, int n_in,
                              void* d_out, int out_size, void* d_ws, size_t ws_size,
                              hipStream_t stream) {
    const float* x = (const float*)d_in[0];   // 8*128*256*256 fp32
    const float* k = (const float*)d_in[1];   // 16 fp32 (4x4 FIR kernel)
    float* out = (float*)d_out;

    dim3 grid(8, 1024);   // 8 row-chunks x (B*C = 1024) planes
    blur_kernel<<<grid, 256, 0, stream>>>(x, k, out);
}